// Round 7
// baseline (183.107 us; speedup 1.0000x reference)
//
#include <hip/hip_runtime.h>

// pred/target (4,4,64,128,128) fp32 -> 16 volumes of 64x128x128.
#define NB 16
#define DD 64
#define HH 128
#define WW 128
#define HW (HH * WW)

constexpr int CD = 4;                  // output planes per block
constexpr int TH = 8;                  // output rows per block
constexpr int LZ = CD + 2;             // 6 input planes
constexpr int LY = TH + 2;             // 10 input rows
constexpr int PL = LY * WW;            // LDS plane stride (floats) = 1280
constexpr int NPOS = LZ * LY * (WW / 4); // 1920 float4 slots
constexpr float INV_COUNT = 1.0f / 50331648.0f; // 1/(3*16*64*128*128)

__global__ void zero_out_kernel(float* out) {
    if (threadIdx.x == 0 && blockIdx.x == 0) out[0] = 0.0f;
}

__global__ __launch_bounds__(256) void sobel_l1_kernel(
    const float* __restrict__ pred,
    const float* __restrict__ target,
    float* __restrict__ out)
{
    __shared__ float t[LZ * PL];       // 6*10*128 floats = 30 KB
    __shared__ float wsum[4];

    const int tid = threadIdx.x;
    // --- decorrelating block swizzle: bn (4 MB) and bc (256 KB) in LOW bits ---
    int b = blockIdx.x;
    const int bn = b & 15; b >>= 4;    // 16 volumes      (4 MB apart)
    const int bc = b & 15; b >>= 4;    // 16 d-chunks     (256 KB apart)
    const int bh = b;                  // 16 h-tiles      (4 KB apart)

    const int h0 = bh * TH;
    const int d0 = bc * CD;
    const size_t nbase = (size_t)bn * (size_t)(DD * HW);

    // Per-block rotation of the load order (multiple of 32 slots = whole rows,
    // so wave coalescing is untouched; bijection on [0,2048)).
    const int rot = ((blockIdx.x * 37) & 63) << 5;

    // ---- one-shot tile load: all loads independent, clamped+masked ----
#pragma unroll
    for (int k = 0; k < 8; ++k) {
        const int i = ((k * 256 + tid + rot) & 2047);  // rotated slot id
        if (i < NPOS) {
            const int q4 = i & 31;
            const int ry = i >> 5;     // 0..59
            const int z  = ry / LY;
            const int y  = ry - z * LY;
            const int gd = d0 - 1 + z;
            const int gh = h0 - 1 + y;
            const bool ok = ((unsigned)gd < DD) && ((unsigned)gh < HH);
            const int gdc = min(max(gd, 0), DD - 1);
            const int ghc = min(max(gh, 0), HH - 1);
            const size_t idx = nbase + (size_t)gdc * HW + (size_t)ghc * WW + 4 * q4;
            const float4 p = *(const float4*)(pred + idx);
            const float4 q = *(const float4*)(target + idx);
            const float m = ok ? 1.0f : 0.0f;
            const float4 v = float4{(p.x - q.x) * m, (p.y - q.y) * m,
                                    (p.z - q.z) * m, (p.w - q.w) * m};
            *(float4*)&t[z * PL + y * WW + 4 * q4] = v;
        }
    }
    __syncthreads();                   // the only barrier before reduction

    // ---- compute from LDS: thread owns 4 w's of one h-row, marches z ----
    const int tc = tid & 31;           // w-quad
    const int lh = tid >> 5;           // 0..7 output row in tile

    // Per-plane partials: A = s(h)s(w)v, Bh = d(h)s(w)v, Bw = s(h)d(w)v.
    auto plane_l = [&](int z, float4& A_, float4& Bh_, float4& Bw_) {
        float4 rs[3], rdw[3];
#pragma unroll
        for (int r = 0; r < 3; ++r) {
            const float4 v = *(const float4*)&t[z * PL + (lh + r) * WW + 4 * tc];
            float lm = __shfl_up(v.w, 1, 32);
            float rp = __shfl_down(v.x, 1, 32);
            if (tc == 0)  lm = 0.f;    // w = -1: volume border
            if (tc == 31) rp = 0.f;    // w = 128: volume border
            rs[r]  = float4{lm  + 2.f * v.x + v.y,
                            v.x + 2.f * v.y + v.z,
                            v.y + 2.f * v.z + v.w,
                            v.z + 2.f * v.w + rp};
            rdw[r] = float4{v.y - lm, v.z - v.x, v.w - v.y, rp - v.z};
        }
        A_  = float4{rs[0].x + 2.f * rs[1].x + rs[2].x,
                     rs[0].y + 2.f * rs[1].y + rs[2].y,
                     rs[0].z + 2.f * rs[1].z + rs[2].z,
                     rs[0].w + 2.f * rs[1].w + rs[2].w};
        Bh_ = float4{rs[2].x - rs[0].x, rs[2].y - rs[0].y,
                     rs[2].z - rs[0].z, rs[2].w - rs[0].w};
        Bw_ = float4{rdw[0].x + 2.f * rdw[1].x + rdw[2].x,
                     rdw[0].y + 2.f * rdw[1].y + rdw[2].y,
                     rdw[0].z + 2.f * rdw[1].z + rdw[2].z,
                     rdw[0].w + 2.f * rdw[1].w + rdw[2].w};
    };

    float4 rA[3], rBh[3], rBw[3];
    plane_l(0, rA[0], rBh[0], rBw[0]);
    plane_l(1, rA[1], rBh[1], rBw[1]);

    float acc = 0.0f;
#pragma unroll
    for (int ld = 0; ld < CD; ++ld) {
        const int s0 = ld % 3, s1 = (ld + 1) % 3, s2 = (ld + 2) % 3;
        plane_l(ld + 2, rA[s2], rBh[s2], rBw[s2]);

        const float4 a0 = rA[s0],  a2 = rA[s2];
        const float4 b0 = rBh[s0], b1 = rBh[s1], b2 = rBh[s2];
        const float4 c0 = rBw[s0], c1 = rBw[s1], c2 = rBw[s2];
        acc += fabsf(a2.x - a0.x) + fabsf(a2.y - a0.y)
             + fabsf(a2.z - a0.z) + fabsf(a2.w - a0.w);
        acc += fabsf(b0.x + 2.f * b1.x + b2.x) + fabsf(b0.y + 2.f * b1.y + b2.y)
             + fabsf(b0.z + 2.f * b1.z + b2.z) + fabsf(b0.w + 2.f * b1.w + b2.w);
        acc += fabsf(c0.x + 2.f * c1.x + c2.x) + fabsf(c0.y + 2.f * c1.y + c2.y)
             + fabsf(c0.z + 2.f * c1.z + c2.z) + fabsf(c0.w + 2.f * c1.w + c2.w);
    }

    // ---- block reduction ----
#pragma unroll
    for (int off = 32; off > 0; off >>= 1)
        acc += __shfl_down(acc, off, 64);
    const int wave = tid >> 6;
    if ((tid & 63) == 0) wsum[wave] = acc;
    __syncthreads();
    if (tid == 0) {
        const float s = wsum[0] + wsum[1] + wsum[2] + wsum[3];
        atomicAdd(out, s * INV_COUNT);
    }
}

extern "C" void kernel_launch(void* const* d_in, const int* in_sizes, int n_in,
                              void* d_out, int out_size, void* d_ws, size_t ws_size,
                              hipStream_t stream) {
    const float* pred   = (const float*)d_in[0];
    const float* target = (const float*)d_in[1];
    float* out = (float*)d_out;

    zero_out_kernel<<<1, 64, 0, stream>>>(out);

    // 16 volumes * 16 d-chunks * 16 h-tiles = 4096 blocks
    const int nblocks = NB * (DD / CD) * (HH / TH);
    sobel_l1_kernel<<<nblocks, 256, 0, stream>>>(pred, target, out);
}

// Round 8
// 152.166 us; speedup vs baseline: 1.2033x; 1.2033x over previous
//
#include <hip/hip_runtime.h>

// pred/target (4,4,64,128,128) fp32 -> 16 volumes of 64x128x128.
#define NB 16
#define DD 64
#define HH 128
#define WW 128
#define HW (HH * WW)

constexpr int CD = 4;                  // output planes per tile
constexpr int TH = 8;                  // output rows per block
constexpr int LZ = CD + 2;             // 6 input planes
constexpr int LY = TH + 2;             // 10 input rows
constexpr int PL = LY * WW;            // LDS plane stride (floats) = 1280
constexpr int NPOS = LZ * LY * (WW / 4); // 1920 float4 slots per tile
constexpr int NT = 8;                  // tiles per block along d (8*4 = 32 planes)
constexpr float INV_COUNT = 1.0f / 50331648.0f; // 1/(3*16*64*128*128)

__global__ void zero_out_kernel(float* out) {
    if (threadIdx.x == 0 && blockIdx.x == 0) out[0] = 0.0f;
}

__global__ __launch_bounds__(256) void sobel_l1_kernel(
    const float* __restrict__ pred,
    const float* __restrict__ target,
    float* __restrict__ out)
{
    __shared__ float t[2][LZ * PL];    // 2 x 30 KB double buffer
    __shared__ float wsum[4];

    const int tid = threadIdx.x;
    int b = blockIdx.x;                // 512 blocks: 16 bh x 2 half x 16 bn
    const int bh   = b & 15; b >>= 4;
    const int half = b & 1;  b >>= 1;
    const int bn   = b;

    const int h0 = bh * TH;
    const int dbase = half * (NT * CD);            // 0 or 32
    const size_t nbase = (size_t)bn * (size_t)(DD * HW);

    // ---- per-slot constants (8 float4 slots per thread per tile) ----
    int  soff[8];   // clamped row offset + 4*q4 (elements within a plane)
    int  sz[8];     // z in 0..5
    bool sokh[8];   // h in range
    bool sval[8];   // slot id < NPOS
#pragma unroll
    for (int k = 0; k < 8; ++k) {
        const int i = k * 256 + tid;
        sval[k] = (i < NPOS);
        const int ii = sval[k] ? i : 0;
        const int q4 = ii & 31;
        const int ry = ii >> 5;
        const int z  = ry / LY;
        const int y  = ry - z * LY;
        const int gh = h0 - 1 + y;
        sokh[k] = (unsigned)gh < HH;
        soff[k] = min(max(gh, 0), HH - 1) * WW + 4 * q4;
        sz[k]   = z;
    }

    float4 sp[8], sq[8];               // raw staging (subtract deferred to store)

    auto load_tile = [&](int tau) {
        const int d0 = dbase + tau * CD;
#pragma unroll
        for (int k = 0; k < 8; ++k) {
            const int gd  = d0 - 1 + sz[k];
            const int gdc = min(max(gd, 0), DD - 1);
            const size_t idx = nbase + (size_t)gdc * HW + soff[k];
            sp[k] = *(const float4*)(pred + idx);
            sq[k] = *(const float4*)(target + idx);
        }
    };

    auto store_tile = [&](int tau, float* B) {
        const int d0 = dbase + tau * CD;
#pragma unroll
        for (int k = 0; k < 8; ++k) {
            if (sval[k]) {
                const int gd = d0 - 1 + sz[k];
                const float m = (sokh[k] && (unsigned)gd < DD) ? 1.0f : 0.0f;
                const int i = k * 256 + tid;
                const float4 v = float4{(sp[k].x - sq[k].x) * m,
                                        (sp[k].y - sq[k].y) * m,
                                        (sp[k].z - sq[k].z) * m,
                                        (sp[k].w - sq[k].w) * m};
                *(float4*)&B[4 * i] = v;   // LDS float-offset = 4*i (contiguous)
            }
        }
    };

    const int tc = tid & 31;           // w-quad
    const int lh = tid >> 5;           // output row in tile

    auto compute_tile = [&](const float* B, float& acc) {
        // Per-plane partials: A = s(h)s(w)v, Bh = d(h)s(w)v, Bw = s(h)d(w)v.
        auto plane_l = [&](int z, float4& A_, float4& Bh_, float4& Bw_) {
            float4 rs[3], rdw[3];
#pragma unroll
            for (int r = 0; r < 3; ++r) {
                const float4 v = *(const float4*)&B[z * PL + (lh + r) * WW + 4 * tc];
                float lm = __shfl_up(v.w, 1, 32);
                float rp = __shfl_down(v.x, 1, 32);
                if (tc == 0)  lm = 0.f;
                if (tc == 31) rp = 0.f;
                rs[r]  = float4{lm  + 2.f * v.x + v.y,
                                v.x + 2.f * v.y + v.z,
                                v.y + 2.f * v.z + v.w,
                                v.z + 2.f * v.w + rp};
                rdw[r] = float4{v.y - lm, v.z - v.x, v.w - v.y, rp - v.z};
            }
            A_  = float4{rs[0].x + 2.f * rs[1].x + rs[2].x,
                         rs[0].y + 2.f * rs[1].y + rs[2].y,
                         rs[0].z + 2.f * rs[1].z + rs[2].z,
                         rs[0].w + 2.f * rs[1].w + rs[2].w};
            Bh_ = float4{rs[2].x - rs[0].x, rs[2].y - rs[0].y,
                         rs[2].z - rs[0].z, rs[2].w - rs[0].w};
            Bw_ = float4{rdw[0].x + 2.f * rdw[1].x + rdw[2].x,
                         rdw[0].y + 2.f * rdw[1].y + rdw[2].y,
                         rdw[0].z + 2.f * rdw[1].z + rdw[2].z,
                         rdw[0].w + 2.f * rdw[1].w + rdw[2].w};
        };

        float4 rA[3], rBh[3], rBw[3];
        plane_l(0, rA[0], rBh[0], rBw[0]);
        plane_l(1, rA[1], rBh[1], rBw[1]);
#pragma unroll
        for (int ld = 0; ld < CD; ++ld) {
            const int s0 = ld % 3, s1 = (ld + 1) % 3, s2 = (ld + 2) % 3;
            plane_l(ld + 2, rA[s2], rBh[s2], rBw[s2]);
            const float4 a0 = rA[s0],  a2 = rA[s2];
            const float4 b0 = rBh[s0], b1 = rBh[s1], b2 = rBh[s2];
            const float4 c0 = rBw[s0], c1 = rBw[s1], c2 = rBw[s2];
            acc += fabsf(a2.x - a0.x) + fabsf(a2.y - a0.y)
                 + fabsf(a2.z - a0.z) + fabsf(a2.w - a0.w);
            acc += fabsf(b0.x + 2.f * b1.x + b2.x) + fabsf(b0.y + 2.f * b1.y + b2.y)
                 + fabsf(b0.z + 2.f * b1.z + b2.z) + fabsf(b0.w + 2.f * b1.w + b2.w);
            acc += fabsf(c0.x + 2.f * c1.x + c2.x) + fabsf(c0.y + 2.f * c1.y + c2.y)
                 + fabsf(c0.z + 2.f * c1.z + c2.z) + fabsf(c0.w + 2.f * c1.w + c2.w);
        }
    };

    // ---- software-pipelined persistent loop over NT tiles ----
    float acc = 0.0f;
    load_tile(0);
    store_tile(0, t[0]);
    __syncthreads();
    for (int tau = 0; tau < NT; ++tau) {
        if (tau + 1 < NT) load_tile(tau + 1);      // in flight during compute
        compute_tile(t[tau & 1], acc);
        if (tau + 1 < NT) store_tile(tau + 1, t[(tau + 1) & 1]);
        __syncthreads();   // one barrier per tile: publishes tile tau+1,
                           // and orders next iter's reads after this store
    }

    // ---- block reduction ----
#pragma unroll
    for (int off = 32; off > 0; off >>= 1)
        acc += __shfl_down(acc, off, 64);
    const int wave = tid >> 6;
    if ((tid & 63) == 0) wsum[wave] = acc;
    __syncthreads();
    if (tid == 0) {
        const float s = wsum[0] + wsum[1] + wsum[2] + wsum[3];
        atomicAdd(out, s * INV_COUNT);
    }
}

extern "C" void kernel_launch(void* const* d_in, const int* in_sizes, int n_in,
                              void* d_out, int out_size, void* d_ws, size_t ws_size,
                              hipStream_t stream) {
    const float* pred   = (const float*)d_in[0];
    const float* target = (const float*)d_in[1];
    float* out = (float*)d_out;

    zero_out_kernel<<<1, 64, 0, stream>>>(out);

    // 16 volumes * 2 d-halves * 16 h-tiles = 512 blocks (all co-resident)
    const int nblocks = NB * 2 * (HH / TH);
    sobel_l1_kernel<<<nblocks, 256, 0, stream>>>(pred, target, out);
}

// Round 9
// 150.103 us; speedup vs baseline: 1.2199x; 1.0137x over previous
//
#include <hip/hip_runtime.h>

// pred/target (4,4,64,128,128) fp32 -> 16 volumes of 64x128x128.
#define NB 16
#define DD 64
#define HH 128
#define WW 128
#define HW (HH * WW)

constexpr int CD = 2;                  // output planes per tile
constexpr int TH = 8;                  // output rows per block
constexpr int LZ = CD + 2;             // 4 input planes per tile
constexpr int LY = TH + 2;             // 10 input rows
constexpr int PL = LY * WW;            // LDS plane stride (floats) = 1280
constexpr int NPOS = LZ * LY * (WW / 4); // 1280 float4 slots per tile
constexpr int SLOTS = NPOS / 256;      // 5 slots per thread
constexpr int NT = 16;                 // tiles per block along d (16*2 = 32 planes)
constexpr float INV_COUNT = 1.0f / 50331648.0f; // 1/(3*16*64*128*128)

__global__ void zero_out_kernel(float* out) {
    if (threadIdx.x == 0 && blockIdx.x == 0) out[0] = 0.0f;
}

__global__ __launch_bounds__(256) void sobel_l1_kernel(
    const float* __restrict__ pred,
    const float* __restrict__ target,
    float* __restrict__ out)
{
    // 2 x 20 KB double buffer = 40960 B exactly (no separate wsum array:
    // final reduction reuses t[0] after the tile loop). 4 blocks/CU.
    __shared__ float t[2][LZ * PL];

    const int tid = threadIdx.x;
    int b = blockIdx.x;                // 512 blocks: 16 bh x 2 half x 16 bn
    const int bh   = b & 15; b >>= 4;
    const int half = b & 1;  b >>= 1;
    const int bn   = b;

    const int h0 = bh * TH;
    const int dbase = half * (NT * CD);            // 0 or 32
    const size_t nbase = (size_t)bn * (size_t)(DD * HW);

    // ---- per-slot constants (5 float4 slots per thread per tile) ----
    int  soff[SLOTS];   // clamped row offset + 4*q4 (elements within a plane)
    int  sz[SLOTS];     // z in 0..3
    bool sokh[SLOTS];   // h in range
#pragma unroll
    for (int k = 0; k < SLOTS; ++k) {
        const int i  = k * 256 + tid;  // 0..1279
        const int q4 = i & 31;
        const int ry = i >> 5;         // 0..39
        const int z  = ry / LY;
        const int y  = ry - z * LY;
        const int gh = h0 - 1 + y;
        sokh[k] = (unsigned)gh < HH;
        soff[k] = min(max(gh, 0), HH - 1) * WW + 4 * q4;
        sz[k]   = z;
    }

    float4 sp[SLOTS], sq[SLOTS];       // raw staging (subtract deferred to store)

    auto load_tile = [&](int tau) {
        const int d0 = dbase + tau * CD;
#pragma unroll
        for (int k = 0; k < SLOTS; ++k) {
            const int gd  = d0 - 1 + sz[k];
            const int gdc = min(max(gd, 0), DD - 1);
            const size_t idx = nbase + (size_t)gdc * HW + soff[k];
            sp[k] = *(const float4*)(pred + idx);
            sq[k] = *(const float4*)(target + idx);
        }
    };

    auto store_tile = [&](int tau, float* B) {
        const int d0 = dbase + tau * CD;
#pragma unroll
        for (int k = 0; k < SLOTS; ++k) {
            const int gd = d0 - 1 + sz[k];
            const float m = (sokh[k] && (unsigned)gd < DD) ? 1.0f : 0.0f;
            const int i = k * 256 + tid;
            const float4 v = float4{(sp[k].x - sq[k].x) * m,
                                    (sp[k].y - sq[k].y) * m,
                                    (sp[k].z - sq[k].z) * m,
                                    (sp[k].w - sq[k].w) * m};
            *(float4*)&B[4 * i] = v;
        }
    };

    const int tc = tid & 31;           // w-quad
    const int lh = tid >> 5;           // output row in tile

    auto compute_tile = [&](const float* B, float& acc) {
        // Per-plane partials: A = s(h)s(w)v, Bh = d(h)s(w)v, Bw = s(h)d(w)v.
        auto plane_l = [&](int z, float4& A_, float4& Bh_, float4& Bw_) {
            float4 rs[3], rdw[3];
#pragma unroll
            for (int r = 0; r < 3; ++r) {
                const float4 v = *(const float4*)&B[z * PL + (lh + r) * WW + 4 * tc];
                float lm = __shfl_up(v.w, 1, 32);
                float rp = __shfl_down(v.x, 1, 32);
                if (tc == 0)  lm = 0.f;
                if (tc == 31) rp = 0.f;
                rs[r]  = float4{lm  + 2.f * v.x + v.y,
                                v.x + 2.f * v.y + v.z,
                                v.y + 2.f * v.z + v.w,
                                v.z + 2.f * v.w + rp};
                rdw[r] = float4{v.y - lm, v.z - v.x, v.w - v.y, rp - v.z};
            }
            A_  = float4{rs[0].x + 2.f * rs[1].x + rs[2].x,
                         rs[0].y + 2.f * rs[1].y + rs[2].y,
                         rs[0].z + 2.f * rs[1].z + rs[2].z,
                         rs[0].w + 2.f * rs[1].w + rs[2].w};
            Bh_ = float4{rs[2].x - rs[0].x, rs[2].y - rs[0].y,
                         rs[2].z - rs[0].z, rs[2].w - rs[0].w};
            Bw_ = float4{rdw[0].x + 2.f * rdw[1].x + rdw[2].x,
                         rdw[0].y + 2.f * rdw[1].y + rdw[2].y,
                         rdw[0].z + 2.f * rdw[1].z + rdw[2].z,
                         rdw[0].w + 2.f * rdw[1].w + rdw[2].w};
        };

        float4 rA[3], rBh[3], rBw[3];
        plane_l(0, rA[0], rBh[0], rBw[0]);
        plane_l(1, rA[1], rBh[1], rBw[1]);
#pragma unroll
        for (int ld = 0; ld < CD; ++ld) {
            const int s0 = ld % 3, s1 = (ld + 1) % 3, s2 = (ld + 2) % 3;
            plane_l(ld + 2, rA[s2], rBh[s2], rBw[s2]);
            const float4 a0 = rA[s0],  a2 = rA[s2];
            const float4 b0 = rBh[s0], b1 = rBh[s1], b2 = rBh[s2];
            const float4 c0 = rBw[s0], c1 = rBw[s1], c2 = rBw[s2];
            acc += fabsf(a2.x - a0.x) + fabsf(a2.y - a0.y)
                 + fabsf(a2.z - a0.z) + fabsf(a2.w - a0.w);
            acc += fabsf(b0.x + 2.f * b1.x + b2.x) + fabsf(b0.y + 2.f * b1.y + b2.y)
                 + fabsf(b0.z + 2.f * b1.z + b2.z) + fabsf(b0.w + 2.f * b1.w + b2.w);
            acc += fabsf(c0.x + 2.f * c1.x + c2.x) + fabsf(c0.y + 2.f * c1.y + c2.y)
                 + fabsf(c0.z + 2.f * c1.z + c2.z) + fabsf(c0.w + 2.f * c1.w + c2.w);
        }
    };

    // ---- software-pipelined persistent loop over NT tiles ----
    float acc = 0.0f;
    load_tile(0);
    store_tile(0, t[0]);
    __syncthreads();
    for (int tau = 0; tau < NT; ++tau) {
        if (tau + 1 < NT) load_tile(tau + 1);      // in flight during compute
        compute_tile(t[tau & 1], acc);
        if (tau + 1 < NT) store_tile(tau + 1, t[(tau + 1) & 1]);
        __syncthreads();   // publishes tile tau+1; orders reads vs next store
    }

    // ---- block reduction (reuse t[0] as wave-sum scratch) ----
#pragma unroll
    for (int off = 32; off > 0; off >>= 1)
        acc += __shfl_down(acc, off, 64);
    if ((tid & 63) == 0) t[0][tid >> 6] = acc;
    __syncthreads();
    if (tid == 0) {
        const float s = t[0][0] + t[0][1] + t[0][2] + t[0][3];
        atomicAdd(out, s * INV_COUNT);
    }
}

extern "C" void kernel_launch(void* const* d_in, const int* in_sizes, int n_in,
                              void* d_out, int out_size, void* d_ws, size_t ws_size,
                              hipStream_t stream) {
    const float* pred   = (const float*)d_in[0];
    const float* target = (const float*)d_in[1];
    float* out = (float*)d_out;

    zero_out_kernel<<<1, 64, 0, stream>>>(out);

    // 16 volumes * 2 d-halves * 16 h-tiles = 512 blocks (all co-resident)
    const int nblocks = NB * 2 * (HH / TH);
    sobel_l1_kernel<<<nblocks, 256, 0, stream>>>(pred, target, out);
}